// Round 3
// baseline (473.730 us; speedup 1.0000x reference)
//
#include <hip/hip_runtime.h>
#include <math.h>

// Problem constants
#define B_  64
#define T_  256
#define IN_ 512
#define HID_ 1024
#define OUT_ 256

// Tiled fp32 GEMM per batch: Out[b] = (GELU?)(A[b] (MxK) @ W[d(b)] (KxN) + bias)
// table layout per domain: K*N weights (row-major KxN) followed by N bias.
template<int M, int N, int K, bool GELU>
__global__ __launch_bounds__(256) void bgemm_kernel(
    const float* __restrict__ X,      // B x M x K
    const float* __restrict__ table,  // D x (K*N + N)
    const int*   __restrict__ hetero, // B x 2 (int32), dom = hetero[2*b]
    float*       __restrict__ Out)    // B x M x N
{
    const int b = blockIdx.z;
    const int d = hetero[2 * b];
    const float* W    = table + (size_t)d * ((size_t)K * N + N);
    const float* bias = W + (size_t)K * N;
    const float* A    = X + (size_t)b * M * K;
    float*       O    = Out + (size_t)b * M * N;

    const int n0 = blockIdx.x * 64;
    const int m0 = blockIdx.y * 64;

    __shared__ float As[16][65];  // [k][m], +1 pad to break bank conflicts on store
    __shared__ float Bs[16][68];  // [k][n], +4 pad keeps float4 alignment, conflict-free

    const int tid = threadIdx.x;  // 0..255
    const int tx = tid & 15;      // n direction (4 cols each)
    const int ty = tid >> 4;      // m direction (4 rows each)

    float acc[4][4] = {};

    for (int kk = 0; kk < K; kk += 16) {
        // A tile: 64 (m) x 16 (k). Thread t loads float4 along k: m=t>>2, k4=(t&3)*4
        {
            const int m  = tid >> 2;
            const int k4 = (tid & 3) * 4;
            const float4 av = *(const float4*)(A + (size_t)(m0 + m) * K + kk + k4);
            As[k4 + 0][m] = av.x;
            As[k4 + 1][m] = av.y;
            As[k4 + 2][m] = av.z;
            As[k4 + 3][m] = av.w;
        }
        // B tile: 16 (k) x 64 (n). Thread t: k=t>>4, n4=(t&15)*4
        {
            const int k  = tid >> 4;
            const int n4 = (tid & 15) * 4;
            const float4 bv = *(const float4*)(W + (size_t)(kk + k) * N + n0 + n4);
            *(float4*)&Bs[k][n4] = bv;
        }
        __syncthreads();

        #pragma unroll
        for (int k = 0; k < 16; ++k) {
            float a[4], bb[4];
            #pragma unroll
            for (int i = 0; i < 4; ++i) a[i] = As[k][ty * 4 + i];
            #pragma unroll
            for (int j = 0; j < 4; ++j) bb[j] = Bs[k][tx * 4 + j];
            #pragma unroll
            for (int i = 0; i < 4; ++i)
                #pragma unroll
                for (int j = 0; j < 4; ++j)
                    acc[i][j] = fmaf(a[i], bb[j], acc[i][j]);
        }
        __syncthreads();
    }

    // Epilogue: bias (+ exact-erf GELU), store
    #pragma unroll
    for (int i = 0; i < 4; ++i) {
        const int m = m0 + ty * 4 + i;
        #pragma unroll
        for (int j = 0; j < 4; ++j) {
            const int n = n0 + tx * 4 + j;
            float v = acc[i][j] + bias[n];
            if (GELU) v = 0.5f * v * (1.0f + erff(v * 0.70710678118654752f));
            O[(size_t)m * N + n] = v;
        }
    }
}

extern "C" void kernel_launch(void* const* d_in, const int* in_sizes, int n_in,
                              void* d_out, int out_size, void* d_ws, size_t ws_size,
                              hipStream_t stream) {
    const float* x          = (const float*)d_in[0];
    const int*   hetero     = (const int*)d_in[1];   // int32 per harness convention
    const float* fc1_table  = (const float*)d_in[2];
    const float* fc2_table  = (const float*)d_in[3];
    float*       out        = (float*)d_out;

    // Workspace: H = B x T x HID fp32 = 64 MiB
    float* H = (float*)d_ws;

    // Kernel 1: H = gelu(X @ W1 + b1); grid (HID/64, T/64, B)
    dim3 g1(HID_ / 64, T_ / 64, B_);
    bgemm_kernel<T_, HID_, IN_, true><<<g1, 256, 0, stream>>>(x, fc1_table, hetero, H);

    // Kernel 2: out = H @ W2 + b2; grid (OUT/64, T/64, B)
    dim3 g2(OUT_ / 64, T_ / 64, B_);
    bgemm_kernel<T_, OUT_, HID_, false><<<g2, 256, 0, stream>>>(H, fc2_table, hetero, out);
}

// Round 5
// 226.732 us; speedup vs baseline: 2.0894x; 2.0894x over previous
//
#include <hip/hip_runtime.h>
#include <math.h>

// Problem constants
#define B_  64
#define T_  256
#define IN_ 512
#define HID_ 1024
#define OUT_ 256

typedef __bf16 bf16_t;
typedef __bf16 bf16x8 __attribute__((ext_vector_type(8)));
typedef float  f32x4  __attribute__((ext_vector_type(4)));

// LDS row stride in bf16 elems: 32 data + 8 pad = 80 B (16B-aligned, bank shift 20 -> 2-way max)
#define LSTR 40

// fp32 -> bf16 round-to-nearest-even, pure bit math (no non-trivially-copyable HIP classes)
__device__ __forceinline__ unsigned f2bf_bits(float f) {
    unsigned u = __builtin_bit_cast(unsigned, f);
    return (u + 0x7FFFu + ((u >> 16) & 1u)) >> 16;
}
__device__ __forceinline__ unsigned pack_bf16x2(float x, float y) {
    return f2bf_bits(x) | (f2bf_bits(y) << 16);
}

// 128x128-tile MFMA GEMM per batch: Out[b] = (GELU?)(A[b] (256xK) @ W[d(b)] (KxN) + bias)
// A is fp32 (A_BF16=false) or bf16 (A_BF16=true). W/bias always fp32 from table.
template<int N_ALL, int K, bool GELU, bool A_BF16, typename OUT_T>
__global__ __launch_bounds__(256) void mfma_bgemm(
    const void*  __restrict__ Ain,    // B x 256 x K
    const float* __restrict__ table,  // D x (K*N_ALL + N_ALL)
    const int*   __restrict__ hetero, // B x 2
    OUT_T*       __restrict__ Out)    // B x 256 x N_ALL
{
    const int b = blockIdx.z;
    const int d = hetero[2 * b];
    const float* W    = table + (size_t)d * ((size_t)K * N_ALL + N_ALL);
    const float* bias = W + (size_t)K * N_ALL;

    const int n0 = blockIdx.x * 128;
    const int m0 = blockIdx.y * 128;

    __shared__ bf16_t LdsA[128 * LSTR];   // [m][k] 10 KB
    __shared__ bf16_t LdsB[128 * LSTR];   // [n][k] 10 KB (transposed W)

    const int tid  = threadIdx.x;
    const int wave = tid >> 6;
    const int lane = tid & 63;
    const int l16  = lane & 15;
    const int quad = lane >> 4;
    const int wm   = (wave >> 1) * 64;    // wave's m-offset inside tile
    const int wn   = (wave & 1) * 64;     // wave's n-offset inside tile

    f32x4 acc[4][4] = {};                 // 4x4 fragments of 16x16

    for (int kk = 0; kk < K; kk += 32) {
        // ---- stage A tile (128m x 32k) into LdsA[m][k] ----
        if constexpr (A_BF16) {
            const bf16_t* A = (const bf16_t*)Ain + (size_t)b * 256 * K;
            const int kc = (tid & 3) * 8;          // 8 bf16 = 16 B chunk
            #pragma unroll
            for (int r = 0; r < 2; ++r) {
                const int m = (tid >> 2) + r * 64;
                uint4 v = *(const uint4*)(A + (size_t)(m0 + m) * K + kk + kc);
                *(uint4*)&LdsA[m * LSTR + kc] = v;
            }
        } else {
            const float* A = (const float*)Ain + (size_t)b * 256 * K;
            const int kc = (tid & 7) * 4;          // 4 fp32 chunk
            #pragma unroll
            for (int r = 0; r < 4; ++r) {
                const int m = (tid >> 3) + r * 32;
                float4 v = *(const float4*)(A + (size_t)(m0 + m) * K + kk + kc);
                uint2 p;
                p.x = pack_bf16x2(v.x, v.y);
                p.y = pack_bf16x2(v.z, v.w);
                *(uint2*)&LdsA[m * LSTR + kc] = p;
            }
        }
        // ---- stage B tile transposed: LdsB[n][k] <- W[kk+k][n0+n] ----
        {
            const int n  = tid & 127;
            const int kb = (tid >> 7) * 16;        // 2 threads split BK=32 per n
            float v[16];
            #pragma unroll
            for (int j = 0; j < 16; ++j)           // n-coalesced dword loads
                v[j] = W[(size_t)(kk + kb + j) * N_ALL + n0 + n];
            uint4 p0, p1;
            p0.x = pack_bf16x2(v[0],  v[1]);  p0.y = pack_bf16x2(v[2],  v[3]);
            p0.z = pack_bf16x2(v[4],  v[5]);  p0.w = pack_bf16x2(v[6],  v[7]);
            p1.x = pack_bf16x2(v[8],  v[9]);  p1.y = pack_bf16x2(v[10], v[11]);
            p1.z = pack_bf16x2(v[12], v[13]); p1.w = pack_bf16x2(v[14], v[15]);
            *(uint4*)&LdsB[n * LSTR + kb]     = p0;
            *(uint4*)&LdsB[n * LSTR + kb + 8] = p1;
        }
        __syncthreads();

        // ---- MFMA: each wave 64x64 = 4x4 fragments ----
        bf16x8 af[4], bfg[4];
        #pragma unroll
        for (int i = 0; i < 4; ++i)
            af[i] = *(const bf16x8*)&LdsA[(wm + i * 16 + l16) * LSTR + quad * 8];
        #pragma unroll
        for (int j = 0; j < 4; ++j)
            bfg[j] = *(const bf16x8*)&LdsB[(wn + j * 16 + l16) * LSTR + quad * 8];
        #pragma unroll
        for (int i = 0; i < 4; ++i)
            #pragma unroll
            for (int j = 0; j < 4; ++j)
                acc[i][j] = __builtin_amdgcn_mfma_f32_16x16x32_bf16(af[i], bfg[j], acc[i][j], 0, 0, 0);
        __syncthreads();
    }

    // ---- epilogue: bias (+ exact-erf GELU), store ----
    // C/D layout: col = lane&15, row = quad*4 + reg  [m89-verified]
    #pragma unroll
    for (int j = 0; j < 4; ++j) {
        const int n = n0 + wn + j * 16 + l16;
        const float bia = bias[n];
        #pragma unroll
        for (int i = 0; i < 4; ++i) {
            const int mbase = m0 + wm + i * 16 + quad * 4;
            #pragma unroll
            for (int r = 0; r < 4; ++r) {
                float vv = acc[i][j][r] + bia;
                if (GELU) vv = 0.5f * vv * (1.0f + erff(vv * 0.70710678f));
                Out[(size_t)b * 256 * N_ALL + (size_t)(mbase + r) * N_ALL + n] = (OUT_T)vv;
            }
        }
    }
}

extern "C" void kernel_launch(void* const* d_in, const int* in_sizes, int n_in,
                              void* d_out, int out_size, void* d_ws, size_t ws_size,
                              hipStream_t stream) {
    const float* x         = (const float*)d_in[0];
    const int*   hetero    = (const int*)d_in[1];
    const float* fc1_table = (const float*)d_in[2];
    const float* fc2_table = (const float*)d_in[3];
    float*       out       = (float*)d_out;

    // Workspace: H = B x T x HID bf16 = 33.5 MB
    bf16_t* H = (bf16_t*)d_ws;

    // fc1: H = gelu(X @ W1 + b1); grid (1024/128, 256/128, 64) = (8,2,64)
    dim3 g1(HID_ / 128, T_ / 128, B_);
    mfma_bgemm<HID_, IN_, true, false, bf16_t><<<g1, 256, 0, stream>>>(
        x, fc1_table, hetero, H);

    // fc2: out = H @ W2 + b2; grid (256/128, 256/128, 64) = (2,2,64)
    dim3 g2(OUT_ / 128, T_ / 128, B_);
    mfma_bgemm<OUT_, HID_, false, true, float><<<g2, 256, 0, stream>>>(
        H, fc2_table, hetero, out);
}

// Round 6
// 213.175 us; speedup vs baseline: 2.2223x; 1.0636x over previous
//
#include <hip/hip_runtime.h>
#include <math.h>

// Problem constants
#define B_  64
#define T_  256
#define IN_ 512
#define HID_ 1024
#define OUT_ 256
#define NDOM 20

typedef __bf16 bf16_t;
typedef __bf16 bf16x8 __attribute__((ext_vector_type(8)));
typedef float  f32x4  __attribute__((ext_vector_type(4)));

// LDS row stride in bf16 elems: 32 data + 8 pad = 80 B (16B-aligned)
#define LSTR 40

// fp32 -> bf16 round-to-nearest-even, pure bit math
__device__ __forceinline__ unsigned f2bf_bits(float f) {
    unsigned u = __builtin_bit_cast(unsigned, f);
    return (u + 0x7FFFu + ((u >> 16) & 1u)) >> 16;
}
__device__ __forceinline__ unsigned pack_bf16x2(float x, float y) {
    return f2bf_bits(x) | (f2bf_bits(y) << 16);
}

// ---------------------------------------------------------------------------
// Pre-pass: per-domain W (K x N fp32, row-major) -> Wt (N x K bf16), bias fp32.
// 64x64 tiles through LDS, coalesced read (along n) and write (along k).
template<int K, int N>
__global__ __launch_bounds__(256) void cvt_transpose(
    const float* __restrict__ table,  // D x (K*N + N)
    bf16_t*      __restrict__ Wt,     // D x N x K
    float*       __restrict__ BiasOut)// D x N
{
    const int d  = blockIdx.z;
    const float* W = table + (size_t)d * ((size_t)K * N + N);
    const int n0 = blockIdx.x * 64;
    const int k0 = blockIdx.y * 64;
    const int tid = threadIdx.x;

    __shared__ float t[64][65];

    #pragma unroll
    for (int r = 0; r < 4; ++r) {
        const int kl = (tid >> 4) + r * 16;
        const int nl = (tid & 15) * 4;
        float4 v = *(const float4*)(W + (size_t)(k0 + kl) * N + n0 + nl);
        t[kl][nl + 0] = v.x; t[kl][nl + 1] = v.y;
        t[kl][nl + 2] = v.z; t[kl][nl + 3] = v.w;
    }
    __syncthreads();

    bf16_t* Wtd = Wt + (size_t)d * K * N;
    #pragma unroll
    for (int r = 0; r < 4; ++r) {
        const int nl = (tid >> 4) + r * 16;
        const int k4 = (tid & 15) * 4;
        uint2 p;
        p.x = pack_bf16x2(t[k4 + 0][nl], t[k4 + 1][nl]);
        p.y = pack_bf16x2(t[k4 + 2][nl], t[k4 + 3][nl]);
        *(uint2*)(Wtd + (size_t)(n0 + nl) * K + k0 + k4) = p;
    }

    if (blockIdx.y == 0 && tid < 64)
        BiasOut[(size_t)d * N + n0 + tid] = W[(size_t)K * N + n0 + tid];
}

// ---------------------------------------------------------------------------
// MFMA GEMM per batch: Out[b] = (GELU?)(A[b] (256xK) @ Wt[d]^T + bias)
// Wt is bf16 [n][k] (pre-transposed). A fp32 (cvt in staging) or bf16 (copy).
// Block tile BM x BN, 4 waves in 2x2, wave tile BM/2 x BN/2.
template<int N_ALL, int K, int BM, int BN, bool GELU, bool A_BF16, typename OUT_T>
__global__ __launch_bounds__(256) void mfma_bgemm(
    const void*   __restrict__ Ain,    // B x 256 x K
    const bf16_t* __restrict__ Wt,     // D x N_ALL x K  (bf16, [n][k])
    const float*  __restrict__ Bias,   // D x N_ALL
    const int*    __restrict__ hetero, // B x 2
    OUT_T*        __restrict__ Out)    // B x 256 x N_ALL
{
    constexpr int FI = BM / 32;   // fragments per wave in m
    constexpr int FJ = BN / 32;   // fragments per wave in n

    const int b = blockIdx.z;
    const int d = hetero[2 * b];
    const bf16_t* W    = Wt + (size_t)d * N_ALL * K;
    const float*  bias = Bias + (size_t)d * N_ALL;

    const int n0 = blockIdx.x * BN;
    const int m0 = blockIdx.y * BM;

    __shared__ bf16_t LdsA[BM * LSTR];
    __shared__ bf16_t LdsB[BN * LSTR];

    const int tid  = threadIdx.x;
    const int wave = tid >> 6;
    const int lane = tid & 63;
    const int l16  = lane & 15;
    const int quad = lane >> 4;
    const int wm   = (wave >> 1) * (BM / 2);
    const int wn   = (wave & 1) * (BN / 2);

    f32x4 acc[FI][FJ] = {};

    for (int kk = 0; kk < K; kk += 32) {
        // ---- stage A tile (BM x 32) into LdsA[m][k] ----
        if constexpr (A_BF16) {
            const bf16_t* A = (const bf16_t*)Ain + (size_t)b * 256 * K;
            const int kc = (tid & 3) * 8;
            #pragma unroll
            for (int r = 0; r < BM / 64; ++r) {
                const int m = (tid >> 2) + r * 64;
                *(uint4*)&LdsA[m * LSTR + kc] =
                    *(const uint4*)(A + (size_t)(m0 + m) * K + kk + kc);
            }
        } else {
            const float* A = (const float*)Ain + (size_t)b * 256 * K;
            const int kc = (tid & 7) * 4;
            #pragma unroll
            for (int r = 0; r < BM / 32; ++r) {
                const int m = (tid >> 3) + r * 32;
                float4 v = *(const float4*)(A + (size_t)(m0 + m) * K + kk + kc);
                uint2 p;
                p.x = pack_bf16x2(v.x, v.y);
                p.y = pack_bf16x2(v.z, v.w);
                *(uint2*)&LdsA[m * LSTR + kc] = p;
            }
        }
        // ---- stage B tile (BN x 32) into LdsB[n][k] — pure uint4 copy ----
        {
            const int kc = (tid & 3) * 8;
            #pragma unroll
            for (int r = 0; r < BN / 64; ++r) {
                const int n = (tid >> 2) + r * 64;
                *(uint4*)&LdsB[n * LSTR + kc] =
                    *(const uint4*)(W + (size_t)(n0 + n) * K + kk + kc);
            }
        }
        __syncthreads();

        // ---- MFMA ----
        bf16x8 af[FI], bfg[FJ];
        #pragma unroll
        for (int i = 0; i < FI; ++i)
            af[i] = *(const bf16x8*)&LdsA[(wm + i * 16 + l16) * LSTR + quad * 8];
        #pragma unroll
        for (int j = 0; j < FJ; ++j)
            bfg[j] = *(const bf16x8*)&LdsB[(wn + j * 16 + l16) * LSTR + quad * 8];
        #pragma unroll
        for (int i = 0; i < FI; ++i)
            #pragma unroll
            for (int j = 0; j < FJ; ++j)
                acc[i][j] = __builtin_amdgcn_mfma_f32_16x16x32_bf16(af[i], bfg[j], acc[i][j], 0, 0, 0);
        __syncthreads();
    }

    // ---- epilogue: bias (+ exact-erf GELU), store ----
    // C/D layout: col = lane&15, row = quad*4 + reg  [m89-verified]
    #pragma unroll
    for (int j = 0; j < FJ; ++j) {
        const int n = n0 + wn + j * 16 + l16;
        const float bia = bias[n];
        #pragma unroll
        for (int i = 0; i < FI; ++i) {
            const int mbase = m0 + wm + i * 16 + quad * 4;
            #pragma unroll
            for (int r = 0; r < 4; ++r) {
                float vv = acc[i][j][r] + bia;
                if (GELU) vv = 0.5f * vv * (1.0f + erff(vv * 0.70710678f));
                Out[(size_t)b * 256 * N_ALL + (size_t)(mbase + r) * N_ALL + n] = (OUT_T)vv;
            }
        }
    }
}

extern "C" void kernel_launch(void* const* d_in, const int* in_sizes, int n_in,
                              void* d_out, int out_size, void* d_ws, size_t ws_size,
                              hipStream_t stream) {
    const float* x         = (const float*)d_in[0];
    const int*   hetero    = (const int*)d_in[1];
    const float* fc1_table = (const float*)d_in[2];
    const float* fc2_table = (const float*)d_in[3];
    float*       out       = (float*)d_out;

    // Workspace layout (total 65,114,112 B < 64 MiB):
    char* ws = (char*)d_ws;
    bf16_t* W1t = (bf16_t*)(ws);                         // 20 x 1024 x 512 bf16 = 20,971,520
    bf16_t* W2t = (bf16_t*)(ws + 20971520);              // 20 x 256 x 1024 bf16 = 10,485,760
    float*  b1  = (float*)(ws + 31457280);               // 20 x 1024 fp32 = 81,920
    float*  b2  = (float*)(ws + 31539200);               // 20 x 256 fp32 = 20,480
    bf16_t* H   = (bf16_t*)(ws + 31559680);              // 64 x 256 x 1024 bf16 = 33,554,432

    // Pre-pass: tables -> bf16 transposed [d][n][k] + fp32 bias
    cvt_transpose<IN_, HID_><<<dim3(HID_ / 64, IN_ / 64, NDOM), 256, 0, stream>>>(
        fc1_table, W1t, b1);
    cvt_transpose<HID_, OUT_><<<dim3(OUT_ / 64, HID_ / 64, NDOM), 256, 0, stream>>>(
        fc2_table, W2t, b2);

    // fc1: H = gelu(X @ W1 + b1); 128x128 tiles, grid (8,2,64)
    mfma_bgemm<HID_, IN_, 128, 128, true, false, bf16_t>
        <<<dim3(HID_ / 128, T_ / 128, B_), 256, 0, stream>>>(x, W1t, b1, hetero, H);

    // fc2: out = H @ W2 + b2; 64x64 tiles for occupancy, grid (4,4,64)
    mfma_bgemm<OUT_, HID_, 64, 64, false, true, float>
        <<<dim3(OUT_ / 64, T_ / 64, B_), 256, 0, stream>>>(H, W2t, b2, hetero, out);
}

// Round 7
// 193.078 us; speedup vs baseline: 2.4536x; 1.1041x over previous
//
#include <hip/hip_runtime.h>
#include <math.h>

// Problem constants
#define B_  64
#define T_  256
#define IN_ 512
#define HID_ 1024
#define OUT_ 256
#define NDOM 20

typedef __bf16 bf16_t;
typedef __bf16 bf16x8 __attribute__((ext_vector_type(8)));
typedef float  f32x4  __attribute__((ext_vector_type(4)));

// fp32 -> bf16 RNE, pure bit math
__device__ __forceinline__ unsigned f2bf_bits(float f) {
    unsigned u = __builtin_bit_cast(unsigned, f);
    return (u + 0x7FFFu + ((u >> 16) & 1u)) >> 16;
}
__device__ __forceinline__ unsigned pack_bf16x2(float x, float y) {
    return f2bf_bits(x) | (f2bf_bits(y) << 16);
}

// Async global->LDS, 16 B per lane. LDS dest = wave-uniform base + lane*16 (m104).
__device__ __forceinline__ void gl_lds16(const void* g, void* l) {
    __builtin_amdgcn_global_load_lds(
        (const __attribute__((address_space(1))) unsigned*)g,
        (__attribute__((address_space(3))) unsigned*)l,
        16, 0, 0);
}

// ---------------------------------------------------------------------------
// Pre-pass: per-domain W (K x N fp32) -> Wt (N x K bf16), bias fp32. (unchanged)
template<int K, int N>
__global__ __launch_bounds__(256) void cvt_transpose(
    const float* __restrict__ table, bf16_t* __restrict__ Wt, float* __restrict__ BiasOut)
{
    const int d  = blockIdx.z;
    const float* W = table + (size_t)d * ((size_t)K * N + N);
    const int n0 = blockIdx.x * 64;
    const int k0 = blockIdx.y * 64;
    const int tid = threadIdx.x;

    __shared__ float t[64][65];

    #pragma unroll
    for (int r = 0; r < 4; ++r) {
        const int kl = (tid >> 4) + r * 16;
        const int nl = (tid & 15) * 4;
        float4 v = *(const float4*)(W + (size_t)(k0 + kl) * N + n0 + nl);
        t[kl][nl + 0] = v.x; t[kl][nl + 1] = v.y;
        t[kl][nl + 2] = v.z; t[kl][nl + 3] = v.w;
    }
    __syncthreads();

    bf16_t* Wtd = Wt + (size_t)d * K * N;
    #pragma unroll
    for (int r = 0; r < 4; ++r) {
        const int nl = (tid >> 4) + r * 16;
        const int k4 = (tid & 15) * 4;
        uint2 p;
        p.x = pack_bf16x2(t[k4 + 0][nl], t[k4 + 1][nl]);
        p.y = pack_bf16x2(t[k4 + 2][nl], t[k4 + 3][nl]);
        *(uint2*)(Wtd + (size_t)(n0 + nl) * K + k0 + k4) = p;
    }

    if (blockIdx.y == 0 && tid < 64)
        BiasOut[(size_t)d * N + n0 + tid] = W[(size_t)K * N + n0 + tid];
}

// ---------------------------------------------------------------------------
// fc1: H[b] = gelu(X[b] (256x512 fp32) @ W1t[d]^T + b1), H bf16.
// 128x128 tile, BK=32. A staged fp32 via global_load_lds (XOR-swizzled, 128B rows);
// B staged bf16 (64B rows). XCD swizzle: 8 n-blocks sharing an X-tile -> same XCD.
__global__ __launch_bounds__(256) void fc1_gemm(
    const float*  __restrict__ X,
    const bf16_t* __restrict__ W1t,   // D x 1024 x 512 bf16 [n][k]
    const float*  __restrict__ Bias,  // D x 1024
    const int*    __restrict__ hetero,
    bf16_t*       __restrict__ H)     // B x 256 x 1024
{
    const int id   = blockIdx.x;          // 1024 blocks
    const int g    = id & 127;            // group shares X-tile; stride-128 ids -> same XCD
    const int nidx = id >> 7;
    const int b    = g >> 1;
    const int m0   = (g & 1) * 128;
    const int n0   = nidx * 128;
    const int d    = hetero[2 * b];
    const bf16_t* W    = W1t + (size_t)d * HID_ * IN_;
    const float*  bias = Bias + (size_t)d * HID_;

    __shared__ __attribute__((aligned(16))) float  LdsA[128 * 32];  // [m][k] fp32, 16 KB
    __shared__ __attribute__((aligned(16))) bf16_t LdsB[128 * 32];  // [n][k] bf16, 8 KB

    const int tid  = threadIdx.x;
    const int wave = tid >> 6;
    const int lane = tid & 63;
    const int l16  = lane & 15;
    const int quad = lane >> 4;
    const int wm   = (wave >> 1) * 64;
    const int wn   = (wave & 1) * 64;

    f32x4 acc[4][4] = {};

    for (int kk = 0; kk < IN_; kk += 32) {
        // A: 128 rows x 128 B, 4 calls/wave. LDS chunk p of row r holds global chunk p^(r&7).
        #pragma unroll
        for (int cc = 0; cc < 4; ++cc) {
            const int r0  = wave * 32 + cc * 8;
            const int row = r0 + (lane >> 3);
            const int cs  = (lane & 7) ^ (row & 7);
            gl_lds16(X + ((size_t)(b * 256 + m0 + row) * IN_ + kk + cs * 4),
                     &LdsA[r0 * 32]);
        }
        // B: 128 rows x 64 B, 2 calls/wave. LDS chunk p of row r holds global chunk p^((r>>1)&3).
        #pragma unroll
        for (int cc = 0; cc < 2; ++cc) {
            const int r0  = wave * 32 + cc * 16;
            const int row = r0 + (lane >> 2);
            const int cs  = (lane & 3) ^ ((row >> 1) & 3);
            gl_lds16(W + (size_t)(n0 + row) * IN_ + kk + cs * 8,
                     &LdsB[r0 * 32]);
        }
        __syncthreads();

        bf16x8 af[4], bfg[4];
        #pragma unroll
        for (int i = 0; i < 4; ++i) {
            const int r  = wm + i * 16 + l16;
            const int c0 = (quad * 2)     ^ (r & 7);
            const int c1 = (quad * 2 + 1) ^ (r & 7);
            float4 f0 = *(const float4*)&LdsA[r * 32 + c0 * 4];
            float4 f1 = *(const float4*)&LdsA[r * 32 + c1 * 4];
            union { bf16x8 v; unsigned u[4]; } a;
            a.u[0] = pack_bf16x2(f0.x, f0.y);
            a.u[1] = pack_bf16x2(f0.z, f0.w);
            a.u[2] = pack_bf16x2(f1.x, f1.y);
            a.u[3] = pack_bf16x2(f1.z, f1.w);
            af[i] = a.v;
        }
        #pragma unroll
        for (int j = 0; j < 4; ++j) {
            const int r  = wn + j * 16 + l16;
            const int cB = quad ^ ((r >> 1) & 3);
            bfg[j] = *(const bf16x8*)&LdsB[r * 32 + cB * 8];
        }
        #pragma unroll
        for (int i = 0; i < 4; ++i)
            #pragma unroll
            for (int j = 0; j < 4; ++j)
                acc[i][j] = __builtin_amdgcn_mfma_f32_16x16x32_bf16(af[i], bfg[j], acc[i][j], 0, 0, 0);
        __syncthreads();
    }

    // Epilogue: bias + exact-erf GELU, store bf16. C/D: col=lane&15, row=quad*4+reg [m89].
    #pragma unroll
    for (int j = 0; j < 4; ++j) {
        const int n = n0 + wn + j * 16 + l16;
        const float bia = bias[n];
        #pragma unroll
        for (int i = 0; i < 4; ++i) {
            const int mbase = m0 + wm + i * 16 + quad * 4;
            #pragma unroll
            for (int r = 0; r < 4; ++r) {
                float vv = acc[i][j][r] + bia;
                vv = 0.5f * vv * (1.0f + erff(vv * 0.70710678f));
                H[((size_t)b * 256 + mbase + r) * HID_ + n] = (bf16_t)vv;
            }
        }
    }
}

// ---------------------------------------------------------------------------
// fc2: out[b] = H[b] (256x1024 bf16) @ W2t[d]^T + b2, fp32 out.
// 64x64 tile, BK=64 (8 MFMA + 8 ds_read per barrier). All-bf16 async staging,
// 128 B rows, chunk^(row&7) swizzle. XCD swizzle: 4 n-blocks share an H-tile.
__global__ __launch_bounds__(256) void fc2_gemm(
    const bf16_t* __restrict__ H,
    const bf16_t* __restrict__ W2t,   // D x 256 x 1024 bf16 [n][k]
    const float*  __restrict__ Bias,  // D x 256
    const int*    __restrict__ hetero,
    float*        __restrict__ Out)   // B x 256 x 256
{
    const int id   = blockIdx.x;          // 1024 blocks
    const int g    = id & 255;            // group shares H-tile; stride-256 ids -> same XCD
    const int nidx = id >> 8;
    const int b    = g >> 2;
    const int m0   = (g & 3) * 64;
    const int n0   = nidx * 64;
    const int d    = hetero[2 * b];
    const bf16_t* W    = W2t + (size_t)d * OUT_ * HID_;
    const float*  bias = Bias + (size_t)d * OUT_;

    __shared__ __attribute__((aligned(16))) bf16_t LdsA[64 * 64];  // [m][k], 8 KB
    __shared__ __attribute__((aligned(16))) bf16_t LdsB[64 * 64];  // [n][k], 8 KB

    const int tid  = threadIdx.x;
    const int wave = tid >> 6;
    const int lane = tid & 63;
    const int l16  = lane & 15;
    const int quad = lane >> 4;
    const int wm   = (wave >> 1) * 32;
    const int wn   = (wave & 1) * 32;

    f32x4 acc[2][2] = {};

    for (int kk = 0; kk < HID_; kk += 64) {
        // A: 64 rows x 128 B, 2 calls/wave.
        #pragma unroll
        for (int cc = 0; cc < 2; ++cc) {
            const int r0  = wave * 16 + cc * 8;
            const int row = r0 + (lane >> 3);
            const int cs  = (lane & 7) ^ (row & 7);
            gl_lds16(H + (size_t)(b * 256 + m0 + row) * HID_ + kk + cs * 8,
                     &LdsA[r0 * 64]);
        }
        // B: 64 rows x 128 B, 2 calls/wave.
        #pragma unroll
        for (int cc = 0; cc < 2; ++cc) {
            const int r0  = wave * 16 + cc * 8;
            const int row = r0 + (lane >> 3);
            const int cs  = (lane & 7) ^ (row & 7);
            gl_lds16(W + (size_t)(n0 + row) * HID_ + kk + cs * 8,
                     &LdsB[r0 * 64]);
        }
        __syncthreads();

        #pragma unroll
        for (int h = 0; h < 2; ++h) {
            bf16x8 af[2], bfg[2];
            #pragma unroll
            for (int i = 0; i < 2; ++i) {
                const int r = wm + i * 16 + l16;
                const int c = (h * 4 + quad) ^ (r & 7);
                af[i] = *(const bf16x8*)&LdsA[r * 64 + c * 8];
            }
            #pragma unroll
            for (int j = 0; j < 2; ++j) {
                const int r = wn + j * 16 + l16;
                const int c = (h * 4 + quad) ^ (r & 7);
                bfg[j] = *(const bf16x8*)&LdsB[r * 64 + c * 8];
            }
            #pragma unroll
            for (int i = 0; i < 2; ++i)
                #pragma unroll
                for (int j = 0; j < 2; ++j)
                    acc[i][j] = __builtin_amdgcn_mfma_f32_16x16x32_bf16(af[i], bfg[j], acc[i][j], 0, 0, 0);
        }
        __syncthreads();
    }

    #pragma unroll
    for (int j = 0; j < 2; ++j) {
        const int n = n0 + wn + j * 16 + l16;
        const float bia = bias[n];
        #pragma unroll
        for (int i = 0; i < 2; ++i) {
            const int mbase = m0 + wm + i * 16 + quad * 4;
            #pragma unroll
            for (int r = 0; r < 4; ++r) {
                Out[((size_t)b * 256 + mbase + r) * OUT_ + n] = acc[i][j][r] + bia;
            }
        }
    }
}

extern "C" void kernel_launch(void* const* d_in, const int* in_sizes, int n_in,
                              void* d_out, int out_size, void* d_ws, size_t ws_size,
                              hipStream_t stream) {
    const float* x         = (const float*)d_in[0];
    const int*   hetero    = (const int*)d_in[1];
    const float* fc1_table = (const float*)d_in[2];
    const float* fc2_table = (const float*)d_in[3];
    float*       out       = (float*)d_out;

    // Workspace layout (65,114,112 B — fits the >=64 MiB ws validated in R6):
    char* ws = (char*)d_ws;
    bf16_t* W1t = (bf16_t*)(ws);                         // 20x1024x512 bf16 = 20,971,520
    bf16_t* W2t = (bf16_t*)(ws + 20971520);              // 20x256x1024 bf16 = 10,485,760
    float*  b1  = (float*)(ws + 31457280);               // 20x1024 fp32
    float*  b2  = (float*)(ws + 31539200);               // 20x256 fp32
    bf16_t* H   = (bf16_t*)(ws + 31559680);              // 64x256x1024 bf16 = 33,554,432

    cvt_transpose<IN_, HID_><<<dim3(HID_ / 64, IN_ / 64, NDOM), 256, 0, stream>>>(
        fc1_table, W1t, b1);
    cvt_transpose<HID_, OUT_><<<dim3(OUT_ / 64, HID_ / 64, NDOM), 256, 0, stream>>>(
        fc2_table, W2t, b2);

    fc1_gemm<<<dim3(1024), 256, 0, stream>>>(x, W1t, b1, hetero, H);
    fc2_gemm<<<dim3(1024), 256, 0, stream>>>(H, W2t, b2, hetero, out);
}

// Round 10
// 188.611 us; speedup vs baseline: 2.5117x; 1.0237x over previous
//
#include <hip/hip_runtime.h>
#include <math.h>

// Problem constants
#define B_  64
#define T_  256
#define IN_ 512
#define HID_ 1024
#define OUT_ 256
#define NDOM 20

typedef __bf16 bf16_t;
typedef __bf16 bf16x8 __attribute__((ext_vector_type(8)));
typedef float  f32x4  __attribute__((ext_vector_type(4)));

// fp32 -> bf16 RNE, pure bit math
__device__ __forceinline__ unsigned f2bf_bits(float f) {
    unsigned u = __builtin_bit_cast(unsigned, f);
    return (u + 0x7FFFu + ((u >> 16) & 1u)) >> 16;
}
__device__ __forceinline__ unsigned pack_bf16x2(float x, float y) {
    return f2bf_bits(x) | (f2bf_bits(y) << 16);
}

// Async global->LDS, 16 B per lane. LDS dest = wave-uniform base + lane*16 (m104).
__device__ __forceinline__ void gl_lds16(const void* g, void* l) {
    __builtin_amdgcn_global_load_lds(
        (const __attribute__((address_space(1))) unsigned*)g,
        (__attribute__((address_space(3))) unsigned*)l,
        16, 0, 0);
}

// ---------------------------------------------------------------------------
// X fp32 -> bf16 (dense copy-convert). 2,097,152 float4s; grid 8192 x 256.
__global__ __launch_bounds__(256) void cvt_x(
    const float* __restrict__ X, bf16_t* __restrict__ Xbf)
{
    const size_t idx = (size_t)blockIdx.x * 256 + threadIdx.x;
    float4 v = ((const float4*)X)[idx];
    uint2 p;
    p.x = pack_bf16x2(v.x, v.y);
    p.y = pack_bf16x2(v.z, v.w);
    ((uint2*)Xbf)[idx] = p;
}

// ---------------------------------------------------------------------------
// Pre-pass: per-domain W (K x N fp32) -> Wt (N x K bf16), bias fp32.
template<int K, int N>
__global__ __launch_bounds__(256) void cvt_transpose(
    const float* __restrict__ table, bf16_t* __restrict__ Wt, float* __restrict__ BiasOut)
{
    const int d  = blockIdx.z;
    const float* W = table + (size_t)d * ((size_t)K * N + N);
    const int n0 = blockIdx.x * 64;
    const int k0 = blockIdx.y * 64;
    const int tid = threadIdx.x;

    __shared__ float t[64][65];

    #pragma unroll
    for (int r = 0; r < 4; ++r) {
        const int kl = (tid >> 4) + r * 16;
        const int nl = (tid & 15) * 4;
        float4 v = *(const float4*)(W + (size_t)(k0 + kl) * N + n0 + nl);
        t[kl][nl + 0] = v.x; t[kl][nl + 1] = v.y;
        t[kl][nl + 2] = v.z; t[kl][nl + 3] = v.w;
    }
    __syncthreads();

    bf16_t* Wtd = Wt + (size_t)d * K * N;
    #pragma unroll
    for (int r = 0; r < 4; ++r) {
        const int nl = (tid >> 4) + r * 16;
        const int k4 = (tid & 15) * 4;
        uint2 p;
        p.x = pack_bf16x2(t[k4 + 0][nl], t[k4 + 1][nl]);
        p.y = pack_bf16x2(t[k4 + 2][nl], t[k4 + 3][nl]);
        *(uint2*)(Wtd + (size_t)(n0 + nl) * K + k0 + k4) = p;
    }

    if (blockIdx.y == 0 && tid < 64)
        BiasOut[(size_t)d * N + n0 + tid] = W[(size_t)K * N + n0 + tid];
}

// ---------------------------------------------------------------------------
// fc1: H[b] = gelu(Xbf[b] (256x512 bf16) @ W1t[d]^T + b1), H bf16.
// 128x128 tile, BK=64, all-bf16 async staging. Swapped-operand MFMA (D^T):
// lane&15 = m, quad*4+reg = 4 consecutive n. Epilogue through LDS for
// fully-coalesced 256 B H-row stores.
#define CT_STRIDE 136   // bf16 elems/row: 128 data + 8 pad = 272 B (16-B mult).
                        // R8/R9 BUG: stride 68/72 < 128-wide tile row -> rows
                        // overlapped -> garbage H. Must be >= 128.
__global__ __launch_bounds__(256) void fc1_gemm(
    const bf16_t* __restrict__ Xbf,   // B x 256 x 512
    const bf16_t* __restrict__ W1t,   // D x 1024 x 512 [n][k]
    const float*  __restrict__ Bias,  // D x 1024
    const int*    __restrict__ hetero,
    bf16_t*       __restrict__ H)     // B x 256 x 1024
{
    const int id   = blockIdx.x;          // 1024 blocks
    const int g    = id & 127;            // stride-128 ids share X-tile -> same XCD
    const int nidx = id >> 7;
    const int b    = g >> 1;
    const int m0   = (g & 1) * 128;
    const int n0   = nidx * 128;
    const int d    = hetero[2 * b];
    const bf16_t* W    = W1t + (size_t)d * HID_ * IN_;
    const float*  bias = Bias + (size_t)d * HID_;
    const bf16_t* A    = Xbf + (size_t)(b * 256 + m0) * IN_;

    __shared__ __attribute__((aligned(16))) char smem[128 * CT_STRIDE * 2];  // 34816 B
    bf16_t* LdsA = (bf16_t*)smem;             // [128][64] 16 KB
    bf16_t* LdsB = (bf16_t*)(smem + 16384);   // [128][64] 16 KB
    bf16_t* Ct   = (bf16_t*)smem;             // epilogue [128][CT_STRIDE] (aliases)

    const int tid  = threadIdx.x;
    const int wave = tid >> 6;
    const int lane = tid & 63;
    const int l16  = lane & 15;
    const int quad = lane >> 4;
    const int wm   = (wave >> 1) * 64;
    const int wn   = (wave & 1) * 64;

    f32x4 acc[4][4] = {};

    for (int kk = 0; kk < IN_; kk += 64) {
        // A: 128 rows x 128 B; 4 calls/wave (8 rows each). chunk cs = p ^ (row&7).
        #pragma unroll
        for (int cc = 0; cc < 4; ++cc) {
            const int r0  = wave * 32 + cc * 8;
            const int row = r0 + (lane >> 3);
            const int cs  = (lane & 7) ^ (row & 7);
            gl_lds16(A + (size_t)row * IN_ + kk + cs * 8, &LdsA[r0 * 64]);
        }
        // B: same shape from W1t rows.
        #pragma unroll
        for (int cc = 0; cc < 4; ++cc) {
            const int r0  = wave * 32 + cc * 8;
            const int row = r0 + (lane >> 3);
            const int cs  = (lane & 7) ^ (row & 7);
            gl_lds16(W + (size_t)(n0 + row) * IN_ + kk + cs * 8, &LdsB[r0 * 64]);
        }
        __syncthreads();

        #pragma unroll
        for (int h = 0; h < 2; ++h) {
            bf16x8 af[4], bfg[4];
            #pragma unroll
            for (int i = 0; i < 4; ++i) {
                const int r = wm + i * 16 + l16;
                const int c = (h * 4 + quad) ^ (r & 7);
                af[i] = *(const bf16x8*)&LdsA[r * 64 + c * 8];
            }
            #pragma unroll
            for (int j = 0; j < 4; ++j) {
                const int r = wn + j * 16 + l16;
                const int c = (h * 4 + quad) ^ (r & 7);
                bfg[j] = *(const bf16x8*)&LdsB[r * 64 + c * 8];
            }
            #pragma unroll
            for (int i = 0; i < 4; ++i)
                #pragma unroll
                for (int j = 0; j < 4; ++j)   // swapped operands -> D^T
                    acc[i][j] = __builtin_amdgcn_mfma_f32_16x16x32_bf16(bfg[j], af[i], acc[i][j], 0, 0, 0);
        }
        __syncthreads();
    }

    // Epilogue: D^T layout: m = wm+i*16+l16, n = wn+j*16+quad*4+reg (4 consecutive).
    // gelu+bias, 8 B ds_writes into Ct.
    #pragma unroll
    for (int i = 0; i < 4; ++i) {
        const int m = wm + i * 16 + l16;
        #pragma unroll
        for (int j = 0; j < 4; ++j) {
            const int nl = wn + j * 16 + quad * 4;
            const float4 b4 = *(const float4*)&bias[n0 + nl];
            float v0 = acc[i][j][0] + b4.x;
            float v1 = acc[i][j][1] + b4.y;
            float v2 = acc[i][j][2] + b4.z;
            float v3 = acc[i][j][3] + b4.w;
            v0 = 0.5f * v0 * (1.0f + erff(v0 * 0.70710678f));
            v1 = 0.5f * v1 * (1.0f + erff(v1 * 0.70710678f));
            v2 = 0.5f * v2 * (1.0f + erff(v2 * 0.70710678f));
            v3 = 0.5f * v3 * (1.0f + erff(v3 * 0.70710678f));
            uint2 p;
            p.x = pack_bf16x2(v0, v1);
            p.y = pack_bf16x2(v2, v3);
            *(uint2*)&Ct[m * CT_STRIDE + nl] = p;
        }
    }
    __syncthreads();

    // Coalesced H store: 128 rows x 256 B.
    #pragma unroll
    for (int it = 0; it < 8; ++it) {
        const int row = it * 16 + (tid >> 4);
        const int ch  = tid & 15;
        uint4 v = *(const uint4*)&Ct[row * CT_STRIDE + ch * 8];
        *(uint4*)&H[((size_t)(b * 256 + m0 + row)) * HID_ + n0 + ch * 8] = v;
    }
}

// ---------------------------------------------------------------------------
// fc2: out[b] = H[b] (256x1024 bf16) @ W2t[d]^T + b2, fp32 out.
// 64x64 tile, BK=64. Swapped-operand MFMA -> direct dwordx4 stores (64 B/row).
__global__ __launch_bounds__(256) void fc2_gemm(
    const bf16_t* __restrict__ H,
    const bf16_t* __restrict__ W2t,   // D x 256 x 1024 [n][k]
    const float*  __restrict__ Bias,  // D x 256
    const int*    __restrict__ hetero,
    float*        __restrict__ Out)   // B x 256 x 256
{
    const int id   = blockIdx.x;          // 1024 blocks
    const int g    = id & 255;            // stride-256 ids share H-tile -> same XCD
    const int nidx = id >> 8;
    const int b    = g >> 2;
    const int m0   = (g & 3) * 64;
    const int n0   = nidx * 64;
    const int d    = hetero[2 * b];
    const bf16_t* W    = W2t + (size_t)d * OUT_ * HID_;
    const float*  bias = Bias + (size_t)d * OUT_;

    __shared__ __attribute__((aligned(16))) bf16_t LdsA[64 * 64];  // 8 KB
    __shared__ __attribute__((aligned(16))) bf16_t LdsB[64 * 64];  // 8 KB

    const int tid  = threadIdx.x;
    const int wave = tid >> 6;
    const int lane = tid & 63;
    const int l16  = lane & 15;
    const int quad = lane >> 4;
    const int wm   = (wave >> 1) * 32;
    const int wn   = (wave & 1) * 32;

    f32x4 acc[2][2] = {};

    for (int kk = 0; kk < HID_; kk += 64) {
        #pragma unroll
        for (int cc = 0; cc < 2; ++cc) {
            const int r0  = wave * 16 + cc * 8;
            const int row = r0 + (lane >> 3);
            const int cs  = (lane & 7) ^ (row & 7);
            gl_lds16(H + (size_t)(b * 256 + m0 + row) * HID_ + kk + cs * 8,
                     &LdsA[r0 * 64]);
        }
        #pragma unroll
        for (int cc = 0; cc < 2; ++cc) {
            const int r0  = wave * 16 + cc * 8;
            const int row = r0 + (lane >> 3);
            const int cs  = (lane & 7) ^ (row & 7);
            gl_lds16(W + (size_t)(n0 + row) * HID_ + kk + cs * 8,
                     &LdsB[r0 * 64]);
        }
        __syncthreads();

        #pragma unroll
        for (int h = 0; h < 2; ++h) {
            bf16x8 af[2], bfg[2];
            #pragma unroll
            for (int i = 0; i < 2; ++i) {
                const int r = wm + i * 16 + l16;
                const int c = (h * 4 + quad) ^ (r & 7);
                af[i] = *(const bf16x8*)&LdsA[r * 64 + c * 8];
            }
            #pragma unroll
            for (int j = 0; j < 2; ++j) {
                const int r = wn + j * 16 + l16;
                const int c = (h * 4 + quad) ^ (r & 7);
                bfg[j] = *(const bf16x8*)&LdsB[r * 64 + c * 8];
            }
            #pragma unroll
            for (int i = 0; i < 2; ++i)
                #pragma unroll
                for (int j = 0; j < 2; ++j)   // swapped operands -> D^T
                    acc[i][j] = __builtin_amdgcn_mfma_f32_16x16x32_bf16(bfg[j], af[i], acc[i][j], 0, 0, 0);
        }
        __syncthreads();
    }

    // Store: m = m0+wm+i*16+l16; n = n0+wn+j*16+quad*4 (+reg). 16 B dwordx4/lane.
    #pragma unroll
    for (int i = 0; i < 2; ++i) {
        const int m = m0 + wm + i * 16 + l16;
        #pragma unroll
        for (int j = 0; j < 2; ++j) {
            const int nl = wn + j * 16 + quad * 4;
            const float4 b4 = *(const float4*)&bias[n0 + nl];
            float4 o;
            o.x = acc[i][j][0] + b4.x;
            o.y = acc[i][j][1] + b4.y;
            o.z = acc[i][j][2] + b4.z;
            o.w = acc[i][j][3] + b4.w;
            *(float4*)&Out[(size_t)(b * 256 + m) * OUT_ + n0 + nl] = o;
        }
    }
}

extern "C" void kernel_launch(void* const* d_in, const int* in_sizes, int n_in,
                              void* d_out, int out_size, void* d_ws, size_t ws_size,
                              hipStream_t stream) {
    const float* x         = (const float*)d_in[0];
    const int*   hetero    = (const int*)d_in[1];
    const float* fc1_table = (const float*)d_in[2];
    const float* fc2_table = (const float*)d_in[3];
    float*       out       = (float*)d_out;

    // Workspace layout (65,114,112 B — same budget validated in R6/R7):
    char* ws = (char*)d_ws;
    bf16_t* W1t = (bf16_t*)(ws);                         // 20x1024x512 bf16 = 20,971,520
    bf16_t* W2t = (bf16_t*)(ws + 20971520);              // 20x256x1024 bf16 = 10,485,760
    float*  b1  = (float*)(ws + 31457280);               // 20x1024 fp32
    float*  b2  = (float*)(ws + 31539200);               // 20x256 fp32
    bf16_t* H   = (bf16_t*)(ws + 31559680);              // 64x256x1024 bf16 = 33,554,432

    // Xbf lives in d_out (16,777,216 B = exactly out_size*4): fc1 reads it,
    // fc2 overwrites d_out afterwards (stream-ordered).
    bf16_t* Xbf = (bf16_t*)d_out;

    cvt_x<<<dim3(8192), 256, 0, stream>>>(x, Xbf);
    cvt_transpose<IN_, HID_><<<dim3(HID_ / 64, IN_ / 64, NDOM), 256, 0, stream>>>(
        fc1_table, W1t, b1);
    cvt_transpose<HID_, OUT_><<<dim3(OUT_ / 64, HID_ / 64, NDOM), 256, 0, stream>>>(
        fc2_table, W2t, b2);

    fc1_gemm<<<dim3(1024), 256, 0, stream>>>(Xbf, W1t, b1, hetero, H);
    fc2_gemm<<<dim3(1024), 256, 0, stream>>>(H, W2t, b2, hetero, out);
}